// Round 1
// baseline (1006.128 us; speedup 1.0000x reference)
//
#include <hip/hip_runtime.h>
#include <hip/hip_bf16.h>

// GraphCastEdgeBlock fused kernel for MI355X (gfx950).
// h = silu(LN(concat(ea, ns[src], nd[dst]) @ W1 + b1)); out = ea + h @ W2 + b2
// E=600000, N=50000, D=128, H=512, in=384. All fp32 I/O; bf16 MFMA compute.

#define E_TOTAL 600000
#define NNODES  50000
#define DD      128
#define HH      512
#define IND     384
#define MTILE   64
#define XS      392   // x LDS row stride (384 + 8 pad) in bf16 elems
#define AS      520   // act LDS row stride (512 + 8 pad)

typedef __attribute__((ext_vector_type(8))) short bf16x8;
typedef __attribute__((ext_vector_type(4))) float f32x4;

__device__ __forceinline__ ushort f2bf(float f) {
    union { float f; unsigned u; } v; v.f = f;
    unsigned u = v.u;
    unsigned r = (u + 0x7fffu + ((u >> 16) & 1u)) >> 16;  // RNE
    return (ushort)r;
}

// Prologue: W1 [384][512] f32 -> W1t [512][384] bf16 ; W2 [512][128] f32 -> W2t [128][512] bf16
__global__ void prep_weights(const float* __restrict__ W1, const float* __restrict__ W2,
                             ushort* __restrict__ W1t, ushort* __restrict__ W2t) {
    int j = blockIdx.x * 256 + threadIdx.x;
    if (j < IND * HH) {                 // W1t[n*384 + k] = W1[k*512 + n]
        int n = j / IND, k = j % IND;
        W1t[j] = f2bf(W1[k * HH + n]);
    }
    int j2 = j - IND * HH;
    if (j2 >= 0 && j2 < HH * DD) {      // W2t[d*512 + k] = W2[k*128 + d]
        int d2 = j2 / HH, k = j2 % HH;
        W2t[j2] = f2bf(W2[k * DD + d2]);
    }
}

__global__ __launch_bounds__(512) void edge_block_kernel(
    const float* __restrict__ edge_attr,
    const float* __restrict__ nsrc,
    const float* __restrict__ ndst,
    const int*   __restrict__ eidx,
    const float* __restrict__ b1,
    const float* __restrict__ g1,
    const float* __restrict__ be1,
    const float* __restrict__ b2,
    const ushort* __restrict__ W1t,
    const ushort* __restrict__ W2t,
    float* __restrict__ out)
{
    __shared__ __align__(16) ushort xbuf[MTILE * AS];  // 66560 B; x phase uses stride XS
    __shared__ float red_s[MTILE][8];
    __shared__ float red_q[MTILE][8];
    __shared__ float stats[MTILE][2];
    __shared__ int   s_idx[2 * MTILE];

    const int tid  = threadIdx.x;
    const int e0   = blockIdx.x * MTILE;
    const int lane = tid & 63;
    const int w    = tid >> 6;          // wave 0..7
    const int g    = lane >> 4;         // quarter-wave 0..3
    const int li   = lane & 15;

    // ---- 1) edge indices ----
    if (tid < 2 * MTILE) {
        int which = tid >> 6;           // 0 = src row, 1 = dst row of edge_index [2][E]
        int r = tid & 63;
        s_idx[tid] = eidx[which * E_TOTAL + e0 + r];
    }
    __syncthreads();

    // ---- 2) stage x tile [64][384] -> LDS bf16 ----
    {
        const int l32 = tid & 31, grp = tid >> 5;    // 16 groups of 32 lanes
        for (int r = grp; r < MTILE; r += 16) {
            const int e = e0 + r;
            float4 ea = *(const float4*)&edge_attr[(size_t)e * DD + l32 * 4];
            float4 sf = *(const float4*)&nsrc[(size_t)s_idx[r] * DD + l32 * 4];
            float4 df = *(const float4*)&ndst[(size_t)s_idx[MTILE + r] * DD + l32 * 4];
            ushort* row = &xbuf[r * XS];
            ushort4 ua = { f2bf(ea.x), f2bf(ea.y), f2bf(ea.z), f2bf(ea.w) };
            ushort4 us = { f2bf(sf.x), f2bf(sf.y), f2bf(sf.z), f2bf(sf.w) };
            ushort4 ud = { f2bf(df.x), f2bf(df.y), f2bf(df.z), f2bf(df.w) };
            *(ushort4*)&row[  0 + l32 * 4] = ua;
            *(ushort4*)&row[128 + l32 * 4] = us;
            *(ushort4*)&row[256 + l32 * 4] = ud;
        }
    }
    __syncthreads();

    // ---- 3) GEMM1: h[64][512] = x @ W1; wave w owns cols [w*64, w*64+64) ----
    const int wn0 = w * 64;
    f32x4 acc[4][4];
    #pragma unroll
    for (int mi = 0; mi < 4; ++mi)
        #pragma unroll
        for (int ni = 0; ni < 4; ++ni)
            acc[mi][ni] = (f32x4){0.f, 0.f, 0.f, 0.f};

    const ushort* w1base = W1t + (size_t)(wn0 + li) * IND + g * 8;

    bf16x8 bcur[4];
    #pragma unroll
    for (int ni = 0; ni < 4; ++ni)
        bcur[ni] = *(const bf16x8*)(w1base + ni * 16 * IND);

    for (int kb = 0; kb < 12; ++kb) {
        bf16x8 bnext[4];
        if (kb < 11) {
            #pragma unroll
            for (int ni = 0; ni < 4; ++ni)
                bnext[ni] = *(const bf16x8*)(w1base + ni * 16 * IND + (kb + 1) * 32);
        }
        const int ko = kb * 32 + g * 8;
        bf16x8 a[4];
        #pragma unroll
        for (int mi = 0; mi < 4; ++mi)
            a[mi] = *(const bf16x8*)&xbuf[(mi * 16 + li) * XS + ko];
        #pragma unroll
        for (int mi = 0; mi < 4; ++mi)
            #pragma unroll
            for (int ni = 0; ni < 4; ++ni)
                acc[mi][ni] = __builtin_amdgcn_mfma_f32_16x16x32_bf16(
                    a[mi], bcur[ni], acc[mi][ni], 0, 0, 0);
        #pragma unroll
        for (int ni = 0; ni < 4; ++ni) bcur[ni] = bnext[ni];
    }

    // ---- bias + row stats (sum, sumsq) ----
    float b1v[4], g1v[4], bev[4];
    #pragma unroll
    for (int ni = 0; ni < 4; ++ni) {
        int c = wn0 + ni * 16 + li;
        b1v[ni] = b1[c]; g1v[ni] = g1[c]; bev[ni] = be1[c];
    }

    #pragma unroll
    for (int mi = 0; mi < 4; ++mi) {
        #pragma unroll
        for (int reg = 0; reg < 4; ++reg) {
            float s = 0.f, q = 0.f;
            #pragma unroll
            for (int ni = 0; ni < 4; ++ni) {
                float h = acc[mi][ni][reg] + b1v[ni];
                acc[mi][ni][reg] = h;
                s += h; q += h * h;
            }
            #pragma unroll
            for (int off = 1; off < 16; off <<= 1) {
                s += __shfl_xor(s, off, 64);
                q += __shfl_xor(q, off, 64);
            }
            if (li == 0) {
                int row = mi * 16 + g * 4 + reg;
                red_s[row][w] = s;
                red_q[row][w] = q;
            }
        }
    }
    __syncthreads();   // all waves done with GEMM1 + partials

    if (tid < MTILE) {
        float s = 0.f, q = 0.f;
        #pragma unroll
        for (int i = 0; i < 8; ++i) { s += red_s[tid][i]; q += red_q[tid][i]; }
        float mu  = s * (1.f / 512.f);
        float var = q * (1.f / 512.f) - mu * mu;
        stats[tid][0] = mu;
        stats[tid][1] = rsqrtf(var + 1e-5f);
    }
    __syncthreads();

    // ---- 4) LN + SiLU, write act bf16 [64][512] to LDS (x region is dead) ----
    #pragma unroll
    for (int mi = 0; mi < 4; ++mi) {
        #pragma unroll
        for (int reg = 0; reg < 4; ++reg) {
            int row = mi * 16 + g * 4 + reg;
            float mu = stats[row][0], rstd = stats[row][1];
            #pragma unroll
            for (int ni = 0; ni < 4; ++ni) {
                float h  = acc[mi][ni][reg];
                float xn = (h - mu) * rstd * g1v[ni] + bev[ni];
                float a  = xn / (1.f + __expf(-xn));     // silu
                xbuf[row * AS + wn0 + ni * 16 + li] = f2bf(a);
            }
        }
    }
    __syncthreads();

    // ---- 5) GEMM2: out[64][128] = act @ W2; wave w owns cols [w*16, w*16+16) ----
    f32x4 acc2[4];
    #pragma unroll
    for (int mi = 0; mi < 4; ++mi) acc2[mi] = (f32x4){0.f, 0.f, 0.f, 0.f};

    const ushort* w2base = W2t + (size_t)(w * 16 + li) * HH + g * 8;
    for (int kb = 0; kb < 16; ++kb) {
        bf16x8 b = *(const bf16x8*)(w2base + kb * 32);
        const int ko = kb * 32 + g * 8;
        #pragma unroll
        for (int mi = 0; mi < 4; ++mi) {
            bf16x8 a2 = *(const bf16x8*)&xbuf[(mi * 16 + li) * AS + ko];
            acc2[mi] = __builtin_amdgcn_mfma_f32_16x16x32_bf16(a2, b, acc2[mi], 0, 0, 0);
        }
    }

    // ---- 6) epilogue: + b2 + edge_attr residual ----
    float b2v = b2[w * 16 + li];
    #pragma unroll
    for (int mi = 0; mi < 4; ++mi) {
        #pragma unroll
        for (int reg = 0; reg < 4; ++reg) {
            int row = mi * 16 + g * 4 + reg;
            size_t o = (size_t)(e0 + row) * DD + w * 16 + li;
            out[o] = acc2[mi][reg] + b2v + edge_attr[o];
        }
    }
}

extern "C" void kernel_launch(void* const* d_in, const int* in_sizes, int n_in,
                              void* d_out, int out_size, void* d_ws, size_t ws_size,
                              hipStream_t stream) {
    const float* edge_attr = (const float*)d_in[0];
    const float* nsrc      = (const float*)d_in[1];
    const float* ndst      = (const float*)d_in[2];
    const int*   eidx      = (const int*)d_in[3];
    const float* W1        = (const float*)d_in[4];
    const float* b1        = (const float*)d_in[5];
    const float* g1        = (const float*)d_in[6];
    const float* be1       = (const float*)d_in[7];
    const float* W2        = (const float*)d_in[8];
    const float* b2        = (const float*)d_in[9];
    float* out = (float*)d_out;

    ushort* W1t = (ushort*)d_ws;             // 512*384 bf16 = 384 KiB
    ushort* W2t = W1t + IND * HH;            // 128*512 bf16 = 128 KiB

    hipLaunchKernelGGL(prep_weights,
                       dim3((IND * HH + HH * DD + 255) / 256), dim3(256), 0, stream,
                       W1, W2, W1t, W2t);

    hipLaunchKernelGGL(edge_block_kernel,
                       dim3(E_TOTAL / MTILE), dim3(512), 0, stream,
                       edge_attr, nsrc, ndst, eidx, b1, g1, be1, b2, W1t, W2t, out);
}

// Round 3
// 713.755 us; speedup vs baseline: 1.4096x; 1.4096x over previous
//
#include <hip/hip_runtime.h>
#include <hip/hip_bf16.h>

// GraphCastEdgeBlock fused kernel for MI355X (gfx950).
// h = silu(LN(concat(ea, ns[src], nd[dst]) @ W1 + b1)); out = ea + h @ W2 + b2
// E=600000, N=50000, D=128, H=512, in=384. fp32 I/O; bf16 MFMA compute.

#define E_TOTAL 600000
#define DD      128
#define HH      512
#define IND     384
#define MTILE   64
#define XS      520   // unified LDS row stride (bf16 elems); 1040 B = 16 mod 128

typedef __attribute__((ext_vector_type(8))) short bf16x8;
typedef __attribute__((ext_vector_type(4))) float f32x4;

__device__ __forceinline__ ushort f2bf(float f) {
    union { float f; unsigned u; } v; v.f = f;
    unsigned u = v.u;
    unsigned r = (u + 0x7fffu + ((u >> 16) & 1u)) >> 16;  // RNE
    return (ushort)r;
}

template <int CTRL>
__device__ __forceinline__ float dpp_add(float x) {
    union { float f; int i; } a, b;
    a.f = x;
    b.i = __builtin_amdgcn_update_dpp(0, a.i, CTRL, 0xf, 0xf, true);
    return x + b.f;
}

// sum across each 16-lane row (all lanes end with the full sum); pure VALU, no DS
__device__ __forceinline__ float row16_sum(float s) {
    s = dpp_add<0xB1>(s);    // quad_perm [1,0,3,2]  (xor 1)
    s = dpp_add<0x4E>(s);    // quad_perm [2,3,0,1]  (xor 2)
    s = dpp_add<0x124>(s);   // row_ror:4
    s = dpp_add<0x128>(s);   // row_ror:8
    return s;
}

// Prologue: W1 [384][512] f32 -> W1t [512][384] bf16 ; W2 [512][128] f32 -> W2t [128][512] bf16
__global__ void prep_weights(const float* __restrict__ W1, const float* __restrict__ W2,
                             ushort* __restrict__ W1t, ushort* __restrict__ W2t) {
    int j = blockIdx.x * 256 + threadIdx.x;
    if (j < IND * HH) {                 // W1t[n*384 + k] = W1[k*512 + n]
        int n = j / IND, k = j % IND;
        W1t[j] = f2bf(W1[k * HH + n]);
    }
    int j2 = j - IND * HH;
    if (j2 >= 0 && j2 < HH * DD) {      // W2t[d*512 + k] = W2[k*128 + d]
        int d2 = j2 / HH, k = j2 % HH;
        W2t[j2] = f2bf(W2[k * DD + d2]);
    }
}

__global__ __launch_bounds__(512, 4) void edge_block_kernel(
    const float* __restrict__ edge_attr,
    const float* __restrict__ nsrc,
    const float* __restrict__ ndst,
    const int*   __restrict__ eidx,
    const float* __restrict__ b1,
    const float* __restrict__ g1,
    const float* __restrict__ be1,
    const float* __restrict__ b2,
    const ushort* __restrict__ W1t,
    const ushort* __restrict__ W2t,
    float* __restrict__ out)
{
    __shared__ __align__(16) ushort xbuf[MTILE * XS];  // 66560 B (x, then act, then f32 out tile)
    __shared__ float red_s[MTILE][8];
    __shared__ float red_q[MTILE][8];
    __shared__ float stats[MTILE][2];

    const int tid  = threadIdx.x;
    const int e0   = blockIdx.x * MTILE;
    const int lane = tid & 63;
    const int w    = tid >> 6;          // wave 0..7
    const int g    = lane >> 4;         // quarter-wave 0..3
    const int li   = lane & 15;

    // ---- 1) stage x tile [64][384] -> LDS bf16 (direct eidx loads, no pre-barrier) ----
    {
        const int l32 = tid & 31, grp = tid >> 5;    // 16 groups of 32 lanes
        #pragma unroll
        for (int it = 0; it < 4; ++it) {
            const int r = grp + it * 16;
            const int e = e0 + r;
            const int si = eidx[e];
            const int di = eidx[E_TOTAL + e];
            float4 ea = *(const float4*)&edge_attr[(size_t)e * DD + l32 * 4];
            float4 sf = *(const float4*)&nsrc[(size_t)si * DD + l32 * 4];
            float4 df = *(const float4*)&ndst[(size_t)di * DD + l32 * 4];
            ushort* row = &xbuf[r * XS];
            ushort4 ua = { f2bf(ea.x), f2bf(ea.y), f2bf(ea.z), f2bf(ea.w) };
            ushort4 us = { f2bf(sf.x), f2bf(sf.y), f2bf(sf.z), f2bf(sf.w) };
            ushort4 ud = { f2bf(df.x), f2bf(df.y), f2bf(df.z), f2bf(df.w) };
            *(ushort4*)&row[  0 + l32 * 4] = ua;
            *(ushort4*)&row[128 + l32 * 4] = us;
            *(ushort4*)&row[256 + l32 * 4] = ud;
        }
    }
    __syncthreads();

    // ---- 2) GEMM1: h[64][512] = x @ W1; wave w owns cols [w*64, w*64+64) ----
    const int wn0 = w * 64;
    f32x4 acc[4][4];
    #pragma unroll
    for (int mi = 0; mi < 4; ++mi)
        #pragma unroll
        for (int ni = 0; ni < 4; ++ni)
            acc[mi][ni] = (f32x4){0.f, 0.f, 0.f, 0.f};

    const ushort* w1p = W1t + (size_t)(wn0 + li) * IND + g * 8;

    bf16x8 B1b[2][4];
    #pragma unroll
    for (int ni = 0; ni < 4; ++ni) B1b[0][ni] = *(const bf16x8*)(w1p + ni * 16 * IND);
    #pragma unroll
    for (int ni = 0; ni < 4; ++ni) B1b[1][ni] = *(const bf16x8*)(w1p + ni * 16 * IND + 32);

    #pragma unroll
    for (int kb = 0; kb < 12; ++kb) {
        const int cur = kb & 1;                  // compile-time after unroll
        const int ko  = kb * 32 + g * 8;
        #pragma unroll
        for (int mi = 0; mi < 4; ++mi) {
            bf16x8 a = *(const bf16x8*)&xbuf[(mi * 16 + li) * XS + ko];
            #pragma unroll
            for (int ni = 0; ni < 4; ++ni)
                acc[mi][ni] = __builtin_amdgcn_mfma_f32_16x16x32_bf16(
                    a, B1b[cur][ni], acc[mi][ni], 0, 0, 0);
        }
        if (kb < 10) {                           // prefetch depth 2
            #pragma unroll
            for (int ni = 0; ni < 4; ++ni)
                B1b[cur][ni] = *(const bf16x8*)(w1p + ni * 16 * IND + (kb + 2) * 32);
        }
    }

    // ---- 3) bias + row stats via DPP row-reduce (no DS ops) ----
    float b1v[4], g1v[4], bev[4];
    #pragma unroll
    for (int ni = 0; ni < 4; ++ni) {
        int c = wn0 + ni * 16 + li;
        b1v[ni] = b1[c]; g1v[ni] = g1[c]; bev[ni] = be1[c];
    }

    #pragma unroll
    for (int mi = 0; mi < 4; ++mi) {
        #pragma unroll
        for (int reg = 0; reg < 4; ++reg) {
            float s = 0.f, q = 0.f;
            #pragma unroll
            for (int ni = 0; ni < 4; ++ni) {
                float h = acc[mi][ni][reg] + b1v[ni];
                acc[mi][ni][reg] = h;
                s += h; q += h * h;
            }
            s = row16_sum(s);
            q = row16_sum(q);
            if (li == 0) {
                int row = mi * 16 + g * 4 + reg;
                red_s[row][w] = s;
                red_q[row][w] = q;
            }
        }
    }
    __syncthreads();

    if (tid < MTILE) {
        float s = 0.f, q = 0.f;
        #pragma unroll
        for (int i = 0; i < 8; ++i) { s += red_s[tid][i]; q += red_q[tid][i]; }
        float mu  = s * (1.f / 512.f);
        float var = q * (1.f / 512.f) - mu * mu;
        stats[tid][0] = mu;
        stats[tid][1] = rsqrtf(var + 1e-5f);
    }
    __syncthreads();

    // ---- 4) preload first half of W2 frags (latency hides under LN phase) ----
    const ushort* w2p = W2t + (size_t)(w * 16 + li) * HH + g * 8;
    bf16x8 B2[16];
    #pragma unroll
    for (int kb = 0; kb < 8; ++kb) B2[kb] = *(const bf16x8*)(w2p + kb * 32);

    // ---- 5) LN + SiLU, write act bf16 [64][512] to LDS (x region is dead) ----
    #pragma unroll
    for (int mi = 0; mi < 4; ++mi) {
        #pragma unroll
        for (int reg = 0; reg < 4; ++reg) {
            int row = mi * 16 + g * 4 + reg;
            float mu = stats[row][0], rstd = stats[row][1];
            #pragma unroll
            for (int ni = 0; ni < 4; ++ni) {
                float h  = acc[mi][ni][reg];
                float xn = (h - mu) * rstd * g1v[ni] + bev[ni];
                float a  = xn / (1.f + __expf(-xn));     // silu
                xbuf[row * XS + wn0 + ni * 16 + li] = f2bf(a);
            }
        }
    }
    __syncthreads();

    // ---- 6) GEMM2: out[64][128] = act @ W2; wave w owns cols [w*16, w*16+16) ----
    f32x4 acc2[4];
    #pragma unroll
    for (int mi = 0; mi < 4; ++mi) acc2[mi] = (f32x4){0.f, 0.f, 0.f, 0.f};

    #pragma unroll
    for (int kb = 0; kb < 16; ++kb) {
        if (kb < 8)                               // depth-8 pipeline for back half
            B2[kb + 8] = *(const bf16x8*)(w2p + (kb + 8) * 32);
        const int ko = kb * 32 + g * 8;
        #pragma unroll
        for (int mi = 0; mi < 4; ++mi) {
            bf16x8 a2 = *(const bf16x8*)&xbuf[(mi * 16 + li) * XS + ko];
            acc2[mi] = __builtin_amdgcn_mfma_f32_16x16x32_bf16(a2, B2[kb], acc2[mi], 0, 0, 0);
        }
    }

    // ---- 7) epilogue: acc2 + b2 -> LDS f32 tile, then coalesced out = tile + edge_attr ----
    float b2v = b2[w * 16 + li];
    float* ldsf = (float*)xbuf;                   // 64 x 132 f32 = 33792 B, fits

    __syncthreads();                              // all waves done reading act
    #pragma unroll
    for (int mi = 0; mi < 4; ++mi) {
        #pragma unroll
        for (int reg = 0; reg < 4; ++reg) {
            int row = mi * 16 + g * 4 + reg;
            ldsf[row * 132 + w * 16 + li] = acc2[mi][reg] + b2v;
        }
    }
    __syncthreads();

    #pragma unroll
    for (int j = 0; j < 4; ++j) {
        int flat = j * 2048 + tid * 4;            // 8192 f32 out tile
        int row = flat >> 7, col = flat & 127;
        float4 v  = *(float4*)&ldsf[row * 132 + col];
        float4 ea = *(const float4*)&edge_attr[(size_t)(e0 + row) * DD + col];
        float4 o = { v.x + ea.x, v.y + ea.y, v.z + ea.z, v.w + ea.w };
        *(float4*)&out[(size_t)(e0 + row) * DD + col] = o;
    }
}

extern "C" void kernel_launch(void* const* d_in, const int* in_sizes, int n_in,
                              void* d_out, int out_size, void* d_ws, size_t ws_size,
                              hipStream_t stream) {
    const float* edge_attr = (const float*)d_in[0];
    const float* nsrc      = (const float*)d_in[1];
    const float* ndst      = (const float*)d_in[2];
    const int*   eidx      = (const int*)d_in[3];
    const float* W1        = (const float*)d_in[4];
    const float* b1        = (const float*)d_in[5];
    const float* g1        = (const float*)d_in[6];
    const float* be1       = (const float*)d_in[7];
    const float* W2        = (const float*)d_in[8];
    const float* b2        = (const float*)d_in[9];
    float* out = (float*)d_out;

    ushort* W1t = (ushort*)d_ws;             // 512*384 bf16 = 384 KiB
    ushort* W2t = W1t + IND * HH;            // 128*512 bf16 = 128 KiB

    hipLaunchKernelGGL(prep_weights,
                       dim3((IND * HH + HH * DD + 255) / 256), dim3(256), 0, stream,
                       W1, W2, W1t, W2t);

    hipLaunchKernelGGL(edge_block_kernel,
                       dim3(E_TOTAL / MTILE), dim3(512), 0, stream,
                       edge_attr, nsrc, ndst, eidx, b1, g1, be1, b2, W1t, W2t, out);
}

// Round 4
// 697.182 us; speedup vs baseline: 1.4431x; 1.0238x over previous
//
#include <hip/hip_runtime.h>
#include <hip/hip_bf16.h>

// GraphCastEdgeBlock fused kernel for MI355X (gfx950).
// h = silu(LN(concat(ea, ns[src], nd[dst]) @ W1 + b1)); out = ea + h @ W2 + b2
// E=600000, N=50000, D=128, H=512, in=384. fp32 I/O; bf16 MFMA compute.

#define E_TOTAL 600000
#define DD      128
#define HH      512
#define IND     384
#define MTILE   64
#define XS      520   // unified LDS row stride (bf16 elems); 1040 B -> row shift 4 words (2-way, free)

typedef __attribute__((ext_vector_type(8))) short bf16x8;
typedef __attribute__((ext_vector_type(4))) float f32x4;

// native converts -> compiler fuses pairs into v_cvt_pk_bf16_f32 (guide m240)
__device__ __forceinline__ ushort f2bf(float f) {
    __hip_bfloat16 b = __float2bfloat16(f);
    return *reinterpret_cast<ushort*>(&b);
}

template <int CTRL>
__device__ __forceinline__ float dpp_add(float x) {
    union { float f; int i; } a, b;
    a.f = x;
    b.i = __builtin_amdgcn_update_dpp(0, a.i, CTRL, 0xf, 0xf, true);
    return x + b.f;
}

// sum across each 16-lane row (all lanes end with the full sum); pure VALU, no DS
__device__ __forceinline__ float row16_sum(float s) {
    s = dpp_add<0xB1>(s);    // quad_perm [1,0,3,2]  (xor 1)
    s = dpp_add<0x4E>(s);    // quad_perm [2,3,0,1]  (xor 2)
    s = dpp_add<0x124>(s);   // row_ror:4
    s = dpp_add<0x128>(s);   // row_ror:8
    return s;
}

// Prologue: W1 [384][512] f32 -> W1t [512][384] bf16 ; W2 [512][128] f32 -> W2t [128][512] bf16
__global__ void prep_weights(const float* __restrict__ W1, const float* __restrict__ W2,
                             ushort* __restrict__ W1t, ushort* __restrict__ W2t) {
    int j = blockIdx.x * 256 + threadIdx.x;
    if (j < IND * HH) {                 // W1t[n*384 + k] = W1[k*512 + n]
        int n = j / IND, k = j % IND;
        W1t[j] = f2bf(W1[k * HH + n]);
    }
    int j2 = j - IND * HH;
    if (j2 >= 0 && j2 < HH * DD) {      // W2t[d*512 + k] = W2[k*128 + d]
        int d2 = j2 / HH, k = j2 % HH;
        W2t[j2] = f2bf(W2[k * DD + d2]);
    }
}

__global__ __launch_bounds__(512, 4) void edge_block_kernel(
    const float* __restrict__ edge_attr,
    const float* __restrict__ nsrc,
    const float* __restrict__ ndst,
    const int*   __restrict__ eidx,
    const float* __restrict__ b1,
    const float* __restrict__ g1,
    const float* __restrict__ be1,
    const float* __restrict__ b2,
    const ushort* __restrict__ W1t,
    const ushort* __restrict__ W2t,
    float* __restrict__ out)
{
    __shared__ __align__(16) ushort xbuf[MTILE * XS];  // 66560 B (x, then act, then f32 out tile)
    __shared__ float red_s[MTILE][8];
    __shared__ float red_q[MTILE][8];
    __shared__ __align__(8) float stats[MTILE][2];

    const int tid  = threadIdx.x;
    const int e0   = blockIdx.x * MTILE;
    const int lane = tid & 63;
    const int w    = tid >> 6;          // wave 0..7
    const int g    = lane >> 4;         // quarter-wave 0..3
    const int li   = lane & 15;

    // ---- 1) stage x tile [64][384] -> LDS bf16 (direct eidx loads, no pre-barrier) ----
    {
        const int l32 = tid & 31, grp = tid >> 5;    // 16 groups of 32 lanes
        #pragma unroll
        for (int it = 0; it < 4; ++it) {
            const int r = grp + it * 16;
            const int e = e0 + r;
            const int si = eidx[e];
            const int di = eidx[E_TOTAL + e];
            float4 ea = *(const float4*)&edge_attr[(size_t)e * DD + l32 * 4];
            float4 sf = *(const float4*)&nsrc[(size_t)si * DD + l32 * 4];
            float4 df = *(const float4*)&ndst[(size_t)di * DD + l32 * 4];
            ushort* row = &xbuf[r * XS];
            ushort4 ua = { f2bf(ea.x), f2bf(ea.y), f2bf(ea.z), f2bf(ea.w) };
            ushort4 us = { f2bf(sf.x), f2bf(sf.y), f2bf(sf.z), f2bf(sf.w) };
            ushort4 ud = { f2bf(df.x), f2bf(df.y), f2bf(df.z), f2bf(df.w) };
            *(ushort4*)&row[  0 + l32 * 4] = ua;
            *(ushort4*)&row[128 + l32 * 4] = us;
            *(ushort4*)&row[256 + l32 * 4] = ud;
        }
    }
    __syncthreads();

    // ---- 2) GEMM1: h[64][512] = x @ W1; wave w owns cols [w*64, w*64+64) ----
    const int wn0 = w * 64;
    f32x4 acc[4][4];
    #pragma unroll
    for (int mi = 0; mi < 4; ++mi)
        #pragma unroll
        for (int ni = 0; ni < 4; ++ni)
            acc[mi][ni] = (f32x4){0.f, 0.f, 0.f, 0.f};

    const ushort* w1p = W1t + (size_t)(wn0 + li) * IND + g * 8;

    bf16x8 B1b[2][4];
    #pragma unroll
    for (int ni = 0; ni < 4; ++ni) B1b[0][ni] = *(const bf16x8*)(w1p + ni * 16 * IND);
    #pragma unroll
    for (int ni = 0; ni < 4; ++ni) B1b[1][ni] = *(const bf16x8*)(w1p + ni * 16 * IND + 32);

    #pragma unroll
    for (int kb = 0; kb < 12; ++kb) {
        const int cur = kb & 1;                  // compile-time after unroll
        const int ko  = kb * 32 + g * 8;
        bf16x8 a[4];
        #pragma unroll
        for (int mi = 0; mi < 4; ++mi)
            a[mi] = *(const bf16x8*)&xbuf[(mi * 16 + li) * XS + ko];
        __builtin_amdgcn_s_setprio(1);
        #pragma unroll
        for (int mi = 0; mi < 4; ++mi)
            #pragma unroll
            for (int ni = 0; ni < 4; ++ni)
                acc[mi][ni] = __builtin_amdgcn_mfma_f32_16x16x32_bf16(
                    a[mi], B1b[cur][ni], acc[mi][ni], 0, 0, 0);
        __builtin_amdgcn_s_setprio(0);
        if (kb < 10) {                           // prefetch depth 2
            #pragma unroll
            for (int ni = 0; ni < 4; ++ni)
                B1b[cur][ni] = *(const bf16x8*)(w1p + ni * 16 * IND + (kb + 2) * 32);
        }
    }

    // ---- 3) bias + row stats via DPP row-reduce (no DS ops) ----
    float b1v[4], g1v[4], bev[4];
    #pragma unroll
    for (int ni = 0; ni < 4; ++ni) {
        int c = wn0 + ni * 16 + li;
        b1v[ni] = b1[c]; g1v[ni] = g1[c]; bev[ni] = be1[c];
    }

    #pragma unroll
    for (int mi = 0; mi < 4; ++mi) {
        #pragma unroll
        for (int reg = 0; reg < 4; ++reg) {
            float s = 0.f, q = 0.f;
            #pragma unroll
            for (int ni = 0; ni < 4; ++ni) {
                float h = acc[mi][ni][reg] + b1v[ni];
                acc[mi][ni][reg] = h;
                s += h;
                q = fmaf(h, h, q);
            }
            s = row16_sum(s);
            q = row16_sum(q);
            if (li == 0) {
                int row = mi * 16 + g * 4 + reg;
                red_s[row][w] = s;
                red_q[row][w] = q;
            }
        }
    }
    __syncthreads();

    if (tid < MTILE) {
        float s = 0.f, q = 0.f;
        #pragma unroll
        for (int i = 0; i < 8; ++i) { s += red_s[tid][i]; q += red_q[tid][i]; }
        float mu  = s * (1.f / 512.f);
        float var = q * (1.f / 512.f) - mu * mu;
        stats[tid][0] = mu;
        stats[tid][1] = rsqrtf(var + 1e-5f);
    }
    __syncthreads();

    // ---- 4) preload first half of W2 frags (latency hides under LN phase) ----
    const ushort* w2p = W2t + (size_t)(w * 16 + li) * HH + g * 8;
    bf16x8 B2[16];
    #pragma unroll
    for (int kb = 0; kb < 8; ++kb) B2[kb] = *(const bf16x8*)(w2p + kb * 32);

    // ---- 5) LN + SiLU (folded affine, rcp-based silu), write act bf16 to LDS ----
    #pragma unroll
    for (int mi = 0; mi < 4; ++mi) {
        #pragma unroll
        for (int reg = 0; reg < 4; ++reg) {
            int row = mi * 16 + g * 4 + reg;
            float2 st = *(float2*)&stats[row][0];     // {mu, rstd}
            #pragma unroll
            for (int ni = 0; ni < 4; ++ni) {
                float sc = st.y * g1v[ni];                       // rstd*gamma
                float tc = fmaf(-st.x, sc, bev[ni]);             // beta - mu*sc
                float xn = fmaf(acc[mi][ni][reg], sc, tc);
                float ex = __expf(-xn);                          // v_mul + v_exp
                float a  = xn * __builtin_amdgcn_rcpf(1.f + ex); // silu, 1-op rcp
                xbuf[row * XS + wn0 + ni * 16 + li] = f2bf(a);
            }
        }
    }
    __syncthreads();

    // ---- 6) GEMM2: out[64][128] = act @ W2; wave w owns cols [w*16, w*16+16) ----
    f32x4 acc2[4];
    #pragma unroll
    for (int mi = 0; mi < 4; ++mi) acc2[mi] = (f32x4){0.f, 0.f, 0.f, 0.f};

    #pragma unroll
    for (int kb = 0; kb < 16; ++kb) {
        if (kb < 8)                               // depth-8 pipeline for back half
            B2[kb + 8] = *(const bf16x8*)(w2p + (kb + 8) * 32);
        const int ko = kb * 32 + g * 8;
        bf16x8 a2[4];
        #pragma unroll
        for (int mi = 0; mi < 4; ++mi)
            a2[mi] = *(const bf16x8*)&xbuf[(mi * 16 + li) * XS + ko];
        __builtin_amdgcn_s_setprio(1);
        #pragma unroll
        for (int mi = 0; mi < 4; ++mi)
            acc2[mi] = __builtin_amdgcn_mfma_f32_16x16x32_bf16(a2[mi], B2[kb], acc2[mi], 0, 0, 0);
        __builtin_amdgcn_s_setprio(0);
    }

    // ---- 7) epilogue: acc2 + b2 -> LDS f32 tile, then coalesced out = tile + edge_attr ----
    float b2v = b2[w * 16 + li];
    float* ldsf = (float*)xbuf;                   // 64 x 132 f32 = 33792 B, fits

    __syncthreads();                              // all waves done reading act
    #pragma unroll
    for (int mi = 0; mi < 4; ++mi) {
        #pragma unroll
        for (int reg = 0; reg < 4; ++reg) {
            int row = mi * 16 + g * 4 + reg;
            ldsf[row * 132 + w * 16 + li] = acc2[mi][reg] + b2v;
        }
    }
    __syncthreads();

    #pragma unroll
    for (int j = 0; j < 4; ++j) {
        int flat = j * 2048 + tid * 4;            // 8192 f32 out tile
        int row = flat >> 7, col = flat & 127;
        float4 v  = *(float4*)&ldsf[row * 132 + col];
        float4 ea = *(const float4*)&edge_attr[(size_t)(e0 + row) * DD + col];
        float4 o = { v.x + ea.x, v.y + ea.y, v.z + ea.z, v.w + ea.w };
        *(float4*)&out[(size_t)(e0 + row) * DD + col] = o;
    }
}

extern "C" void kernel_launch(void* const* d_in, const int* in_sizes, int n_in,
                              void* d_out, int out_size, void* d_ws, size_t ws_size,
                              hipStream_t stream) {
    const float* edge_attr = (const float*)d_in[0];
    const float* nsrc      = (const float*)d_in[1];
    const float* ndst      = (const float*)d_in[2];
    const int*   eidx      = (const int*)d_in[3];
    const float* W1        = (const float*)d_in[4];
    const float* b1        = (const float*)d_in[5];
    const float* g1        = (const float*)d_in[6];
    const float* be1       = (const float*)d_in[7];
    const float* W2        = (const float*)d_in[8];
    const float* b2        = (const float*)d_in[9];
    float* out = (float*)d_out;

    ushort* W1t = (ushort*)d_ws;             // 512*384 bf16 = 384 KiB
    ushort* W2t = W1t + IND * HH;            // 128*512 bf16 = 128 KiB

    hipLaunchKernelGGL(prep_weights,
                       dim3((IND * HH + HH * DD + 255) / 256), dim3(256), 0, stream,
                       W1, W2, W1t, W2t);

    hipLaunchKernelGGL(edge_block_kernel,
                       dim3(E_TOTAL / MTILE), dim3(512), 0, stream,
                       edge_attr, nsrc, ndst, eidx, b1, g1, be1, b2, W1t, W2t, out);
}